// Round 1
// 413.807 us; speedup vs baseline: 1.0383x; 1.0383x over previous
//
#include <hip/hip_runtime.h>

// CausalAttention: B=8, S=2048, D_IN=D_OUT=1024, single head, causal, fp32 I/O.
// Pipeline (all fp16 MFMA 16x16x32, fp32 accum):
//   1. cast x -> xh (fp16); transpose+cast Wq,Wk,Wv -> WT (d_out-major, fp16)
//   2. ca_qkv2: fused QKV GEMM (R5 engine, see below). Q,K row-major; V -> Vt.
//   3. ca_score: U[b,q,k] = exp(q.k/32) fp16, causal tiles only, masked diag
//   4. ca_rowsum: invl[b,q] = 1/sum_k U
//   5. ca_pv: out = (U @ V) * invl   (fp32 stores)
//
// R5: rebuild QKV GEMM around the counted-vmcnt deep pipeline (T3+T4) since
// R4's 2-phase structure was barrier-drain bound (MfmaUtil 32%, VALUBusy 42%):
//  - 256x256 block tile, 512 thr / 8 waves (2M x 4N), wave tile 128x64,
//    acc[8][4]: 2x MFMA per staged byte vs the 128^2 tile.
//  - LDS = 4-deep ring of BK=32 tiles (A+B = 32KB/set, 128 KiB total).
//    Distance-3 prefetch; per K-tile exactly ONE raw s_barrier preceded by
//    s_waitcnt vmcnt(8) (= 2 stage-groups in flight, never drains to 0).
//    Safety: stage(kt+3) overwrites the buffer read at step kt-1; the step-top
//    barrier + lgkmcnt-before-MFMA means those reads retired in registers
//    before any wave can issue the overwriting DMA.
//  - T2 XOR swizzle pc = c ^ ((row>>1)&3) on 16B chunks: applied to the
//    global source of global_load_lds (LDS dest must stay linear) AND to the
//    ds_read address. Kills the 8-way bank conflict (12.6M/dispatch in R4).
//  - s_setprio(1) around the 32-MFMA cluster (T5).
//  - XCD-chunked block swizzle (768 blocks % 8 == 0 -> simple bijective).
// score/pv keep the R4 engine this round.

#define Bv 8
#define Sv 2048
#define Dv 1024
#define BK 32
#define NKT (Dv / BK)  // 32 K-tiles for the QKV GEMM

typedef _Float16 f16x8 __attribute__((ext_vector_type(8)));
typedef _Float16 f16x4 __attribute__((ext_vector_type(4)));
typedef float    f32x4 __attribute__((ext_vector_type(4)));

#define GLL(gp, lp)                                            \
  __builtin_amdgcn_global_load_lds(                            \
      (const __attribute__((address_space(1))) void*)(gp),     \
      (__attribute__((address_space(3))) void*)(lp), 16, 0, 0)

// ---------------------------------------------------------------------------
// R4 engine (kept for ca_score / ca_pv)
// ---------------------------------------------------------------------------
__device__ __forceinline__ void mma_step(const _Float16* As, const _Float16* Bs,
                                         int wm, int wn, int lane, f32x4 acc[4][4]) {
  int ll = lane & 15, quad = lane >> 4;
  f16x8 a[4], b[4];
#pragma unroll
  for (int mi = 0; mi < 4; ++mi)
    a[mi] = *(const f16x8*)(As + (wm * 64 + mi * 16 + ll) * BK + quad * 8);
#pragma unroll
  for (int ni = 0; ni < 4; ++ni)
    b[ni] = *(const f16x8*)(Bs + (wn * 64 + ni * 16 + ll) * BK + quad * 8);
#pragma unroll
  for (int mi = 0; mi < 4; ++mi)
#pragma unroll
    for (int ni = 0; ni < 4; ++ni)
      acc[mi][ni] = __builtin_amdgcn_mfma_f32_16x16x32_f16(a[mi], b[ni], acc[mi][ni], 0, 0, 0);
}

__device__ __forceinline__ void gemm_dbuf(const _Float16* __restrict__ A, int lda,
                                          const _Float16* __restrict__ B, int ldb,
                                          int ktiles, _Float16 (*S)[4096],
                                          f32x4 acc[4][4]) {
  const int tid  = threadIdx.x;
  const int lane = tid & 63, wave = tid >> 6;
  const int wm = wave >> 1, wn = wave & 1;
  const int srow = wave * 32 + (lane >> 2);   // 0..127
  const int scol = (lane & 3) * 8;            // 0,8,16,24
  const int loA0 = srow * lda + scol, loA1 = loA0 + 16 * lda;
  const int loB0 = srow * ldb + scol, loB1 = loB0 + 16 * ldb;
  _Float16* dA = &S[0][wave * 1024];
  _Float16* dB = &S[1][wave * 1024];
  const _Float16* gA = A;
  const _Float16* gB = B;

#define STAGE(bi)                              \
  do {                                         \
    GLL(gA + loA0, dA + (bi) * 8192);          \
    GLL(gA + loA1, dA + (bi) * 8192 + 512);    \
    GLL(gB + loB0, dB + (bi) * 8192);          \
    GLL(gB + loB1, dB + (bi) * 8192 + 512);    \
  } while (0)

  STAGE(0);
  for (int kt = 0; kt < ktiles; kt += 2) {
    __syncthreads();
    gA += BK; gB += BK;
    STAGE(1);
    mma_step(S[0], S[1], wm, wn, lane, acc);
    __syncthreads();
    gA += BK; gB += BK;
    if (kt + 2 < ktiles) STAGE(0);
    mma_step(S[2], S[3], wm, wn, lane, acc);
  }
#undef STAGE
}

#define ZERO_ACC(acc)                              \
  _Pragma("unroll") for (int i_ = 0; i_ < 4; ++i_) \
  _Pragma("unroll") for (int j_ = 0; j_ < 4; ++j_) \
      acc[i_][j_] = (f32x4){0.f, 0.f, 0.f, 0.f};

// --- 1a. cast x (fp32) -> fp16, 8 elems/thread ---
__global__ __launch_bounds__(256) void ca_cast(const float* __restrict__ x,
                                               _Float16* __restrict__ y) {
  int i = (blockIdx.x * 256 + threadIdx.x) * 8;
  f32x4 a = *(const f32x4*)(x + i);
  f32x4 b = *(const f32x4*)(x + i + 4);
  f16x8 h;
#pragma unroll
  for (int j = 0; j < 4; ++j) { h[j] = (_Float16)a[j]; h[4 + j] = (_Float16)b[j]; }
  *(f16x8*)(y + i) = h;
}

// --- 1b. transpose+cast W (K x N fp32) -> WT (N x K fp16) ---
__global__ __launch_bounds__(256) void ca_transpose(const float* __restrict__ W0,
                                                    const float* __restrict__ W1,
                                                    const float* __restrict__ W2,
                                                    _Float16* __restrict__ T0,
                                                    _Float16* __restrict__ T1,
                                                    _Float16* __restrict__ T2) {
  const float* W = blockIdx.z == 0 ? W0 : blockIdx.z == 1 ? W1 : W2;
  _Float16* WT   = blockIdx.z == 0 ? T0 : blockIdx.z == 1 ? T1 : T2;
  __shared__ _Float16 t[32][33];
  int k0 = blockIdx.x * 32, n0 = blockIdx.y * 32;
  int r = threadIdx.x >> 5, c = threadIdx.x & 31;
#pragma unroll
  for (int i = 0; i < 4; ++i)
    t[r + i * 8][c] = (_Float16)W[(size_t)(k0 + r + i * 8) * Dv + n0 + c];
  __syncthreads();
#pragma unroll
  for (int i = 0; i < 4; ++i)
    WT[(size_t)(n0 + r + i * 8) * Dv + k0 + c] = t[c][r + i * 8];
}

// ---------------------------------------------------------------------------
// --- 2. R5 fused QKV projection: 256x256 tile, counted-vmcnt 4-deep ring ---
// grid: 768 blocks x 512 thr. nt = 0..11 of 256 cols: 0-3 Q, 4-7 K, 8-11 V.
// ---------------------------------------------------------------------------
__global__ __launch_bounds__(512, 2) void ca_qkv2(const _Float16* __restrict__ X,
                                                  const _Float16* __restrict__ WTq,
                                                  const _Float16* __restrict__ WTk,
                                                  const _Float16* __restrict__ WTv,
                                                  _Float16* __restrict__ Q,
                                                  _Float16* __restrict__ K,
                                                  _Float16* __restrict__ Vt) {
  __shared__ _Float16 As[4][256 * BK];   // 4 x 16 KB
  __shared__ _Float16 Bs[4][256 * BK];   // 4 x 16 KB  -> 128 KiB total

  // XCD-chunked bijective swizzle: 768 % 8 == 0. Consecutive logical ids
  // (which share an A panel: nt fastest) land on the same XCD's L2.
  int id  = blockIdx.x;
  int swz = (id & 7) * 96 + (id >> 3);
  int my  = swz / 12, nt = swz - my * 12;
  int m0  = my * 256;
  int which = nt >> 2;
  int n0  = (nt & 3) * 256;
  const _Float16* WT = which == 0 ? WTq : which == 1 ? WTk : WTv;
  const _Float16* gA = X + (size_t)m0 * Dv;
  const _Float16* gB = WT + (size_t)n0 * Dv;

  const int tid  = threadIdx.x;
  const int lane = tid & 63, wave = tid >> 6;
  const int wm = wave >> 2, wn = wave & 3;          // 2M x 4N waves
  const int ll = lane & 15, quad = lane >> 4;
  // T2 swizzle: physical 16B chunk = logical ^ ((row>>1)&3).
  const int cw   = (lane >> 1) & 3;                 // == ((row>>1)&3) for row=..+ll
  const int cofs = (quad ^ cw) << 3;                // elems
  const int aoff = (wm * 128 + ll) * BK + cofs;     // + mi*512 (DS imm)
  const int boff = (wn * 64 + ll) * BK + cofs;      // + ni*512 (DS imm)
  // Staging: wave stages rows [wave*32, wave*32+32). Lane covers row lane>>2
  // (+16 for 2nd load), logical chunk (lane&3) ^ ((lane>>3)&3)  (pre-swizzled
  // global source; GLL's LDS dest is linear: base + lane*16B).
  const int srow = wave * 32 + (lane >> 2);
  const int scol = (((lane & 3) ^ ((lane >> 3) & 3)) << 3);
  const int loA0 = srow * Dv + scol, loA1 = loA0 + 16 * Dv;  // lda == ldb == Dv

#define QSTAGE(ktp, p)                              \
  do {                                              \
    const _Float16* ga_ = gA + (ktp) * BK;          \
    const _Float16* gb_ = gB + (ktp) * BK;          \
    GLL(ga_ + loA0, &As[p][wave * 1024]);           \
    GLL(ga_ + loA1, &As[p][wave * 1024 + 512]);     \
    GLL(gb_ + loA0, &Bs[p][wave * 1024]);           \
    GLL(gb_ + loA1, &Bs[p][wave * 1024 + 512]);     \
  } while (0)

  f32x4 acc[8][4];
#pragma unroll
  for (int i = 0; i < 8; ++i)
#pragma unroll
    for (int j = 0; j < 4; ++j) acc[i][j] = (f32x4){0.f, 0.f, 0.f, 0.f};

  QSTAGE(0, 0); QSTAGE(1, 1); QSTAGE(2, 2);   // 12 GLLs in flight

  // Per K-tile: wait own stage(kt) landed (vmcnt(8) = keep newest 2 stage
  // groups in flight), barrier (=> everyone's stage(kt) landed AND everyone
  // retired reads of buf[(kt+3)&3]), then issue stage(kt+3), then 12 ds_read
  // + 32 MFMA. Compiler handles lgkmcnt for ds_read->MFMA; asm "memory"
  // clobber + sched_barrier(0) pin loads below the wait/barrier (rule #18).
#define QSTEP(ktc, p)                                                         \
  do {                                                                        \
    asm volatile("s_waitcnt vmcnt(8)" ::: "memory");                          \
    __builtin_amdgcn_s_barrier();                                             \
    __builtin_amdgcn_sched_barrier(0);                                        \
    if ((ktc) + 3 < NKT) QSTAGE((ktc) + 3, ((p) + 3) & 3);                    \
    const _Float16* Ap_ = As[p];                                              \
    const _Float16* Bp_ = Bs[p];                                              \
    f16x8 a_[8], b_[4];                                                       \
    _Pragma("unroll") for (int mi = 0; mi < 8; ++mi)                          \
        a_[mi] = *(const f16x8*)(Ap_ + aoff + mi * (16 * BK));                \
    _Pragma("unroll") for (int ni = 0; ni < 4; ++ni)                          \
        b_[ni] = *(const f16x8*)(Bp_ + boff + ni * (16 * BK));                \
    __builtin_amdgcn_s_setprio(1);                                            \
    _Pragma("unroll") for (int mi = 0; mi < 8; ++mi)                          \
      _Pragma("unroll") for (int ni = 0; ni < 4; ++ni)                        \
          acc[mi][ni] = __builtin_amdgcn_mfma_f32_16x16x32_f16(               \
              a_[mi], b_[ni], acc[mi][ni], 0, 0, 0);                          \
    __builtin_amdgcn_s_setprio(0);                                            \
  } while (0)

#pragma unroll 1
  for (int kt = 0; kt < NKT; kt += 4) {
    QSTEP(kt + 0, 0);
    QSTEP(kt + 1, 1);
    QSTEP(kt + 2, 2);
    QSTEP(kt + 3, 3);
  }
#undef QSTEP
#undef QSTAGE

  // Epilogue: same C-fragment mapping as R4 (col = ll side, row = quad*4+r).
  if (which < 2) {
    _Float16* Out = which == 0 ? Q : K;
#pragma unroll
    for (int mi = 0; mi < 8; ++mi)
#pragma unroll
      for (int ni = 0; ni < 4; ++ni) {
        int gc = n0 + wn * 64 + ni * 16 + ll;
#pragma unroll
        for (int r = 0; r < 4; ++r) {
          int gr = m0 + wm * 128 + mi * 16 + quad * 4 + r;
          Out[(size_t)gr * Dv + gc] = (_Float16)acc[mi][ni][r];
        }
      }
  } else {
    // Vt: [d_out][B*S]; 4 regs = 4 consecutive rows -> contiguous 8B store
#pragma unroll
    for (int mi = 0; mi < 8; ++mi)
#pragma unroll
      for (int ni = 0; ni < 4; ++ni) {
        int gc = n0 + wn * 64 + ni * 16 + ll;
        int gr = m0 + wm * 128 + mi * 16 + quad * 4;
        f16x4 v;
#pragma unroll
        for (int r = 0; r < 4; ++r) v[r] = (_Float16)acc[mi][ni][r];
        *(f16x4*)(Vt + (size_t)gc * (Bv * Sv) + gr) = v;
      }
  }
}

// --- 3. scores: U = exp(QK^T / 32), causal tiles only ---
__global__ __launch_bounds__(256) void ca_score(const _Float16* __restrict__ Q,
                                                const _Float16* __restrict__ Km,
                                                _Float16* __restrict__ U) {
  int kt = blockIdx.x, qt = blockIdx.y, b = blockIdx.z;
  if (kt > qt) return;
  __shared__ _Float16 S[4][4096];
  f32x4 acc[4][4];
  ZERO_ACC(acc);
  const _Float16* Qb = Q + ((size_t)b * Sv + qt * 128) * Dv;
  const _Float16* Kb = Km + ((size_t)b * Sv + kt * 128) * Dv;
  gemm_dbuf(Qb, Dv, Kb, Dv, Dv / BK, S, acc);
  int lane = threadIdx.x & 63, wave = threadIdx.x >> 6;
  int wm = wave >> 1, wn = wave & 1, ll = lane & 15, quad = lane >> 4;
#pragma unroll
  for (int mi = 0; mi < 4; ++mi)
#pragma unroll
    for (int ni = 0; ni < 4; ++ni) {
      int kc = kt * 128 + wn * 64 + ni * 16 + ll;
#pragma unroll
      for (int r = 0; r < 4; ++r) {
        int qr = qt * 128 + wm * 64 + mi * 16 + quad * 4 + r;
        float s = acc[mi][ni][r] * 0.03125f;  // 1/sqrt(1024)
        float u = (kc > qr) ? 0.f : __expf(fminf(fmaxf(s, -15.f), 10.f));
        U[((size_t)b * Sv + qr) * Sv + kc] = (_Float16)u;
      }
    }
}

// --- 4. row sums -> 1/l ---
__global__ __launch_bounds__(256) void ca_rowsum(const _Float16* __restrict__ U,
                                                 float* __restrict__ invl) {
  int rg = blockIdx.x;
  int b = rg >> 11, q = rg & (Sv - 1);
  int lim = ((q >> 7) + 1) << 7;
  const _Float16* row = U + ((size_t)b * Sv + q) * Sv;
  float s = 0.f;
  for (int k = threadIdx.x * 8; k < lim; k += 2048) {
    f16x8 v = *(const f16x8*)(row + k);
#pragma unroll
    for (int j = 0; j < 8; ++j) s += (float)v[j];
  }
#pragma unroll
  for (int o = 32; o >= 1; o >>= 1) s += __shfl_down(s, o);
  __shared__ float wsum[4];
  if ((threadIdx.x & 63) == 0) wsum[threadIdx.x >> 6] = s;
  __syncthreads();
  if (threadIdx.x == 0) invl[rg] = 1.f / (wsum[0] + wsum[1] + wsum[2] + wsum[3]);
}

// --- 5. PV GEMM: out = (U @ V) * invl ---
__global__ __launch_bounds__(256) void ca_pv(const _Float16* __restrict__ U,
                                             const _Float16* __restrict__ Vt,
                                             const float* __restrict__ invl,
                                             float* __restrict__ Out) {
  int nt = blockIdx.x, qt = blockIdx.y, b = blockIdx.z;
  __shared__ _Float16 S[4][4096];
  f32x4 acc[4][4];
  ZERO_ACC(acc);
  const _Float16* Ab = U + ((size_t)b * Sv + qt * 128) * Sv;
  const _Float16* Bb = Vt + (size_t)(nt * 128) * (Bv * Sv) + (size_t)b * Sv;
  gemm_dbuf(Ab, Sv, Bb, Bv * Sv, (qt + 1) * 4, S, acc);   // ktiles multiple of 4
  int lane = threadIdx.x & 63, wave = threadIdx.x >> 6;
  int wm = wave >> 1, wn = wave & 1, ll = lane & 15, quad = lane >> 4;
#pragma unroll
  for (int mi = 0; mi < 4; ++mi)
#pragma unroll
    for (int ni = 0; ni < 4; ++ni) {
      int oc = nt * 128 + wn * 64 + ni * 16 + ll;
#pragma unroll
      for (int r = 0; r < 4; ++r) {
        int qr = qt * 128 + wm * 64 + mi * 16 + quad * 4 + r;
        Out[((size_t)b * Sv + qr) * Dv + oc] = acc[mi][ni][r] * invl[b * Sv + qr];
      }
    }
}

extern "C" void kernel_launch(void* const* d_in, const int* in_sizes, int n_in,
                              void* d_out, int out_size, void* d_ws, size_t ws_size,
                              hipStream_t stream) {
  const float* x  = (const float*)d_in[0];
  const float* Wq = (const float*)d_in[1];
  const float* Wk = (const float*)d_in[2];
  const float* Wv = (const float*)d_in[3];
  float* out = (float*)d_out;

  char* ws = (char*)d_ws;
  size_t off = 0;
  const size_t M = (size_t)Bv * Sv;           // 16384
  _Float16* xh  = (_Float16*)(ws + off); off += M * Dv * 2;        // 32 MB
  _Float16* WTq = (_Float16*)(ws + off); off += (size_t)Dv * Dv * 2;
  _Float16* WTk = (_Float16*)(ws + off); off += (size_t)Dv * Dv * 2;
  _Float16* WTv = (_Float16*)(ws + off); off += (size_t)Dv * Dv * 2;
  _Float16* Q   = (_Float16*)(ws + off); off += M * Dv * 2;        // 32 MB
  _Float16* Km  = (_Float16*)(ws + off); off += M * Dv * 2;        // 32 MB
  _Float16* Vt  = (_Float16*)(ws + off); off += M * Dv * 2;        // 32 MB (transposed)
  _Float16* U   = (_Float16*)(ws + off); off += (size_t)Bv * Sv * Sv * 2;  // 64 MB
  float*    invl = (float*)(ws + off);   off += M * 4;

  ca_cast<<<(M * Dv) / (8 * 256), 256, 0, stream>>>(x, xh);
  ca_transpose<<<dim3(32, 32, 3), 256, 0, stream>>>(Wq, Wk, Wv, WTq, WTk, WTv);

  ca_qkv2<<<dim3(768), 512, 0, stream>>>(xh, WTq, WTk, WTv, Q, Km, Vt);

  ca_score<<<dim3(Sv / 128, Sv / 128, Bv), 256, 0, stream>>>(Q, Km, U);
  ca_rowsum<<<M, 256, 0, stream>>>(U, invl);
  ca_pv<<<dim3(Dv / 128, Sv / 128, Bv), 256, 0, stream>>>(U, Vt, invl, out);
}

// Round 3
// 405.181 us; speedup vs baseline: 1.0604x; 1.0213x over previous
//
#include <hip/hip_runtime.h>

// CausalAttention: B=8, S=2048, D_IN=D_OUT=1024, single head, causal, fp32 I/O.
// Pipeline (all fp16 MFMA 16x16x32, fp32 accum):
//   1. cast x -> xh (fp16); transpose+cast Wq,Wk,Wv -> WT (d_out-major, fp16)
//   2. ca_qkv3: fused QKV GEMM (R7 fine-phase engine). Q,K row-major; V -> Vt.
//   3. ca_score: U[b,q,k] = exp(q.k/32) fp16, causal tiles only, masked diag
//   4. ca_rowsum: invl[b,q] = 1/sum_k U
//   5. ca_pv: out = (U @ V) * invl   (fp32 stores)
//
// R7 == R6 (m201-style 4-phase/K64 pipeline) + two safety fences after the
// R6 container failure (suspected infra, but audit found one WAR window):
//  - sched_barrier(0) after p2's closing barrier: pins p3's B-stage DMA
//    below all reads of slot 4d+2 (the only intra-tile WAR; raw s_barrier
//    is not a compiler memory fence).
//  - every phase opens with {s_barrier; lgkmcnt(0); sched_barrier(0)} --
//    byte-for-byte the verified m201 template.
// Design recap:
//  - 256x256 tile, 512 thr / 8 waves (2Mx4N), BK=64 K-tiles, 4 phases/tile,
//    16 MFMA/phase, 2 barriers/phase.
//  - LDS = 8 half-slots x 16KB (2-tile double buffer, 128 KiB). Per tile t
//    (parity d=t&1): A ht0 -> slot 4d+0, A ht1 -> 4d+1, B ht0 -> 4d+2,
//    B ht1 -> 4d+3. Stages: tile t issues A0(t+1), A1(t+1), B1(t+1), B0(t+2).
//  - Gate: s_waitcnt vmcnt(2) once per tile (1 half-stage stays in flight);
//    never 0 in the steady loop; vmcnt(0) at tile 14 covers the tail.
//  - T2 16B-chunk XOR swizzle pc = c ^ (row&7): pre-swizzled global source
//    (GLL dest linear) + swizzled ds_read -> conflict-free.
//  - setprio(1) around each MFMA cluster; XCD-chunked block swizzle.
// score/pv keep the R4 engine this round.

#define Bv 8
#define Sv 2048
#define Dv 1024
#define BK 32
#define NT 16   // K64 tiles in the QKV GEMM (1024/64)

typedef _Float16 f16x8 __attribute__((ext_vector_type(8)));
typedef _Float16 f16x4 __attribute__((ext_vector_type(4)));
typedef float    f32x4 __attribute__((ext_vector_type(4)));

#define GLL(gp, lp)                                            \
  __builtin_amdgcn_global_load_lds(                            \
      (const __attribute__((address_space(1))) void*)(gp),     \
      (__attribute__((address_space(3))) void*)(lp), 16, 0, 0)

// ---------------------------------------------------------------------------
// R4 engine (kept for ca_score / ca_pv)
// ---------------------------------------------------------------------------
__device__ __forceinline__ void mma_step(const _Float16* As, const _Float16* Bs,
                                         int wm, int wn, int lane, f32x4 acc[4][4]) {
  int ll = lane & 15, quad = lane >> 4;
  f16x8 a[4], b[4];
#pragma unroll
  for (int mi = 0; mi < 4; ++mi)
    a[mi] = *(const f16x8*)(As + (wm * 64 + mi * 16 + ll) * BK + quad * 8);
#pragma unroll
  for (int ni = 0; ni < 4; ++ni)
    b[ni] = *(const f16x8*)(Bs + (wn * 64 + ni * 16 + ll) * BK + quad * 8);
#pragma unroll
  for (int mi = 0; mi < 4; ++mi)
#pragma unroll
    for (int ni = 0; ni < 4; ++ni)
      acc[mi][ni] = __builtin_amdgcn_mfma_f32_16x16x32_f16(a[mi], b[ni], acc[mi][ni], 0, 0, 0);
}

__device__ __forceinline__ void gemm_dbuf(const _Float16* __restrict__ A, int lda,
                                          const _Float16* __restrict__ B, int ldb,
                                          int ktiles, _Float16 (*S)[4096],
                                          f32x4 acc[4][4]) {
  const int tid  = threadIdx.x;
  const int lane = tid & 63, wave = tid >> 6;
  const int wm = wave >> 1, wn = wave & 1;
  const int srow = wave * 32 + (lane >> 2);   // 0..127
  const int scol = (lane & 3) * 8;            // 0,8,16,24
  const int loA0 = srow * lda + scol, loA1 = loA0 + 16 * lda;
  const int loB0 = srow * ldb + scol, loB1 = loB0 + 16 * ldb;
  _Float16* dA = &S[0][wave * 1024];
  _Float16* dB = &S[1][wave * 1024];
  const _Float16* gA = A;
  const _Float16* gB = B;

#define STAGE(bi)                              \
  do {                                         \
    GLL(gA + loA0, dA + (bi) * 8192);          \
    GLL(gA + loA1, dA + (bi) * 8192 + 512);    \
    GLL(gB + loB0, dB + (bi) * 8192);          \
    GLL(gB + loB1, dB + (bi) * 8192 + 512);    \
  } while (0)

  STAGE(0);
  for (int kt = 0; kt < ktiles; kt += 2) {
    __syncthreads();
    gA += BK; gB += BK;
    STAGE(1);
    mma_step(S[0], S[1], wm, wn, lane, acc);
    __syncthreads();
    gA += BK; gB += BK;
    if (kt + 2 < ktiles) STAGE(0);
    mma_step(S[2], S[3], wm, wn, lane, acc);
  }
#undef STAGE
}

#define ZERO_ACC(acc)                              \
  _Pragma("unroll") for (int i_ = 0; i_ < 4; ++i_) \
  _Pragma("unroll") for (int j_ = 0; j_ < 4; ++j_) \
      acc[i_][j_] = (f32x4){0.f, 0.f, 0.f, 0.f};

// --- 1a. cast x (fp32) -> fp16, 8 elems/thread ---
__global__ __launch_bounds__(256) void ca_cast(const float* __restrict__ x,
                                               _Float16* __restrict__ y) {
  int i = (blockIdx.x * 256 + threadIdx.x) * 8;
  f32x4 a = *(const f32x4*)(x + i);
  f32x4 b = *(const f32x4*)(x + i + 4);
  f16x8 h;
#pragma unroll
  for (int j = 0; j < 4; ++j) { h[j] = (_Float16)a[j]; h[4 + j] = (_Float16)b[j]; }
  *(f16x8*)(y + i) = h;
}

// --- 1b. transpose+cast W (K x N fp32) -> WT (N x K fp16) ---
__global__ __launch_bounds__(256) void ca_transpose(const float* __restrict__ W0,
                                                    const float* __restrict__ W1,
                                                    const float* __restrict__ W2,
                                                    _Float16* __restrict__ T0,
                                                    _Float16* __restrict__ T1,
                                                    _Float16* __restrict__ T2) {
  const float* W = blockIdx.z == 0 ? W0 : blockIdx.z == 1 ? W1 : W2;
  _Float16* WT   = blockIdx.z == 0 ? T0 : blockIdx.z == 1 ? T1 : T2;
  __shared__ _Float16 t[32][33];
  int k0 = blockIdx.x * 32, n0 = blockIdx.y * 32;
  int r = threadIdx.x >> 5, c = threadIdx.x & 31;
#pragma unroll
  for (int i = 0; i < 4; ++i)
    t[r + i * 8][c] = (_Float16)W[(size_t)(k0 + r + i * 8) * Dv + n0 + c];
  __syncthreads();
#pragma unroll
  for (int i = 0; i < 4; ++i)
    WT[(size_t)(n0 + r + i * 8) * Dv + k0 + c] = t[c][r + i * 8];
}

// ---------------------------------------------------------------------------
// --- 2. R7 fused QKV projection: 256x256 tile, 4 fine phases per K64 tile ---
// grid: 768 blocks x 512 thr. nt = 0..11 of 256 cols: 0-3 Q, 4-7 K, 8-11 V.
// ---------------------------------------------------------------------------
__global__ __launch_bounds__(512, 2) void ca_qkv3(const _Float16* __restrict__ X,
                                                  const _Float16* __restrict__ WTq,
                                                  const _Float16* __restrict__ WTk,
                                                  const _Float16* __restrict__ WTv,
                                                  _Float16* __restrict__ Q,
                                                  _Float16* __restrict__ K,
                                                  _Float16* __restrict__ Vt) {
  // 8 half-slots x 16KB. Tile t parity d: A ht -> slot 4d+ht, B ht -> 4d+2+ht.
  // Within-half: [128 rows][64 f16]; 16B chunk pc holds logical chunk
  // pc ^ (row&7) (T2 swizzle).
  __shared__ _Float16 L[8][8192];

  // XCD-chunked bijective swizzle: 768 % 8 == 0.
  int id  = blockIdx.x;
  int swz = (id & 7) * 96 + (id >> 3);
  int my  = swz / 12, nt = swz - my * 12;
  int m0  = my * 256;
  int which = nt >> 2;
  int n0  = (nt & 3) * 256;
  const _Float16* WT = which == 0 ? WTq : which == 1 ? WTk : WTv;
  const _Float16* gA = X + (size_t)m0 * Dv;
  const _Float16* gB = WT + (size_t)n0 * Dv;

  const int tid  = threadIdx.x;
  const int lane = tid & 63, wave = tid >> 6;
  const int wm = wave >> 2, wn = wave & 3;          // 2M x 4N waves, tile 128x64
  const int ll = lane & 15, quad = lane >> 4;

  // --- staging geometry (pre-swizzled global source; linear GLL dest) ---
  // thread t, load l: LDS linear off (l*512 + t)*16B -> row r = l*64+wave*8+
  // (lane>>3), phys chunk = lane&7 -> logical chunk = (lane&7)^(r&7).
  const int laneRow = wave * 8 + (lane >> 3);
  const int laneCol = (((lane & 7) ^ ((lane >> 3) & 7)) << 3);  // elems
  const int gOff0 = laneRow * Dv + laneCol;
  const int gOff1 = (64 + laneRow) * Dv + laneCol;
  _Float16* Ldst = &L[0][0] + wave * 512;           // wave-uniform

  // --- read geometry: frag (row lr, ks): phys chunk = (ks*4+quad)^(ll&7) ---
  const int sw0 = ((quad ^ (ll & 7)) << 3);         // ks=0, elems
  _Float16* Lb = &L[0][0];
  const _Float16* pA0 = Lb + wm * 8192 + ll * 64 + sw0;
  const _Float16* pA1 = Lb + wm * 8192 + ll * 64 + (sw0 ^ 32);
  const _Float16* pB0 = Lb + 16384 + (wn >> 1) * 8192 + (wn & 1) * 4096 + ll * 64 + sw0;
  const _Float16* pB1 = Lb + 16384 + (wn >> 1) * 8192 + (wn & 1) * 4096 + ll * 64 + (sw0 ^ 32);

#define STG(slot, mat, ht, kpf)                                   \
  do {                                                            \
    const _Float16* g_ = (mat) + (size_t)((ht) * 128 * Dv + (kpf) * 64); \
    GLL(g_ + gOff0, Ldst + (slot) * 8192);                        \
    GLL(g_ + gOff1, Ldst + (slot) * 8192 + 4096);                 \
  } while (0)

#define RD_A(P, d, mh)                                            \
  _Pragma("unroll") for (int i_ = 0; i_ < 4; ++i_)                \
      a[i_] = *(const f16x8*)((P) + (d) * 32768 + ((mh) * 4 + i_) * 1024);
#define RD_B(P, d)                                                \
  _Pragma("unroll") for (int i_ = 0; i_ < 4; ++i_)                \
      b[i_] = *(const f16x8*)((P) + (d) * 32768 + i_ * 1024);
#define MMA(mh)                                                   \
  __builtin_amdgcn_s_setprio(1);                                  \
  _Pragma("unroll") for (int i_ = 0; i_ < 4; ++i_)                \
  _Pragma("unroll") for (int j_ = 0; j_ < 4; ++j_)                \
      acc[(mh) * 4 + i_][j_] = __builtin_amdgcn_mfma_f32_16x16x32_f16( \
          a[i_], b[j_], acc[(mh) * 4 + i_], 0, 0, 0)[0] == 0.f    \
          ? __builtin_amdgcn_mfma_f32_16x16x32_f16(a[i_], b[j_], acc[(mh) * 4 + i_][j_], 0, 0, 0) \
          : __builtin_amdgcn_mfma_f32_16x16x32_f16(a[i_], b[j_], acc[(mh) * 4 + i_][j_], 0, 0, 0); \
  __builtin_amdgcn_s_setprio(0);
#undef MMA
#define MMA(mh)                                                   \
  __builtin_amdgcn_s_setprio(1);                                  \
  _Pragma("unroll") for (int i_ = 0; i_ < 4; ++i_)                \
  _Pragma("unroll") for (int j_ = 0; j_ < 4; ++j_)                \
      acc[(mh) * 4 + i_][j_] = __builtin_amdgcn_mfma_f32_16x16x32_f16( \
          a[i_], b[j_], acc[(mh) * 4 + i_][j_], 0, 0, 0);         \
  __builtin_amdgcn_s_setprio(0);
#define BAR() __builtin_amdgcn_s_barrier()
#define WAITV_(n) asm volatile("s_waitcnt vmcnt(" #n ")" ::: "memory")
#define WAITV(n) WAITV_(n)
// Phase opening: the verified m201 template verbatim -- rendezvous, ISA-level
// drain of this wave's pre-barrier ds_reads, motion fence (rule #18).
#define PH_OPEN()                                                 \
  BAR();                                                          \
  asm volatile("s_waitcnt lgkmcnt(0)" ::: "memory");              \
  __builtin_amdgcn_sched_barrier(0)

  // Per tile (kk, parity d): 4 phases {ds_read; stage 1 half; PH_OPEN; MFMA;
  // bar}.  p0: A[mh0,ks0]+B[ks0], stage A0(kk+1);  p1: A[mh1,ks0], stage
  // A1(kk+1);  p2: A[mh0,ks1]+B[ks1], stage B1(kk+1);  p3: A[mh1,ks1], stage
  // B0(kk+2).  Extra sched_barrier(0) before p3: p3's stage overwrites slot
  // 4d+2 which p0/p2 of THIS tile read -- pin the DMA below those reads.
  // Gate vmcnt(G) before the tile-boundary barrier.
#define TILEG(kk, d, G)                                           \
  do {                                                            \
    f16x8 a[4], b[4];                                             \
    RD_A(pA0, d, 0); RD_B(pB0, d);                                \
    if ((kk) + 1 < NT) STG(4 * (1 - (d)) + 0, gA, 0, (kk) + 1);   \
    PH_OPEN(); MMA(0); BAR();                                     \
    RD_A(pA0, d, 1);                                              \
    if ((kk) + 1 < NT) STG(4 * (1 - (d)) + 1, gA, 1, (kk) + 1);   \
    PH_OPEN(); MMA(1); BAR();                                     \
    RD_A(pA1, d, 0); RD_B(pB1, d);                                \
    if ((kk) + 1 < NT) STG(4 * (1 - (d)) + 3, gB, 1, (kk) + 1);   \
    PH_OPEN(); MMA(0); BAR();                                     \
    __builtin_amdgcn_sched_barrier(0);                            \
    RD_A(pA1, d, 1);                                              \
    if ((kk) + 2 < NT) STG(4 * (d) + 2, gB, 0, (kk) + 2);         \
    PH_OPEN(); MMA(1);                                            \
    WAITV(G); BAR();                                              \
    __builtin_amdgcn_sched_barrier(0);                            \
  } while (0)

  f32x4 acc[8][4];
#pragma unroll
  for (int i = 0; i < 8; ++i)
#pragma unroll
    for (int j = 0; j < 4; ++j) acc[i][j] = (f32x4){0.f, 0.f, 0.f, 0.f};

  // Prologue: stage B0(0),A0(0),A1(0),B1(0),B0(1) (oldest-first), gate.
  STG(2, gB, 0, 0);
  STG(0, gA, 0, 0);
  STG(1, gA, 1, 0);
  STG(3, gB, 1, 0);
  STG(6, gB, 0, 1);
  WAITV(2); BAR();
  __builtin_amdgcn_sched_barrier(0);

#pragma unroll 1
  for (int kk = 0; kk < NT - 2; kk += 2) {   // tiles 0..13
    TILEG(kk, 0, 2);
    TILEG(kk + 1, 1, 2);
  }
  TILEG(14, 0, 0);   // tail: drain fully once (tile 15 gets no p3 stage after)
  TILEG(15, 1, 2);

#undef TILEG
#undef PH_OPEN
#undef MMA
#undef RD_A
#undef RD_B
#undef STG

  // Epilogue: same C-fragment mapping as R5 (passed harness).
  if (which < 2) {
    _Float16* Out = which == 0 ? Q : K;
#pragma unroll
    for (int mi = 0; mi < 8; ++mi)
#pragma unroll
      for (int ni = 0; ni < 4; ++ni) {
        int gc = n0 + wn * 64 + ni * 16 + ll;
#pragma unroll
        for (int r = 0; r < 4; ++r) {
          int gr = m0 + wm * 128 + mi * 16 + quad * 4 + r;
          Out[(size_t)gr * Dv + gc] = (_Float16)acc[mi][ni][r];
        }
      }
  } else {
    // Vt: [d_out][B*S]; 4 regs = 4 consecutive rows -> contiguous 8B store
#pragma unroll
    for (int mi = 0; mi < 8; ++mi)
#pragma unroll
      for (int ni = 0; ni < 4; ++ni) {
        int gc = n0 + wn * 64 + ni * 16 + ll;
        int gr = m0 + wm * 128 + mi * 16 + quad * 4;
        f16x4 v;
#pragma unroll
        for (int r = 0; r < 4; ++r) v[r] = (_Float16)acc[mi][ni][r];
        *(f16x4*)(Vt + (size_t)gc * (Bv * Sv) + gr) = v;
      }
  }
}

// --- 3. scores: U = exp(QK^T / 32), causal tiles only ---
__global__ __launch_bounds__(256) void ca_score(const _Float16* __restrict__ Q,
                                                const _Float16* __restrict__ Km,
                                                _Float16* __restrict__ U) {
  int kt = blockIdx.x, qt = blockIdx.y, b = blockIdx.z;
  if (kt > qt) return;
  __shared__ _Float16 S[4][4096];
  f32x4 acc[4][4];
  ZERO_ACC(acc);
  const _Float16* Qb = Q + ((size_t)b * Sv + qt * 128) * Dv;
  const _Float16* Kb = Km + ((size_t)b * Sv + kt * 128) * Dv;
  gemm_dbuf(Qb, Dv, Kb, Dv, Dv / BK, S, acc);
  int lane = threadIdx.x & 63, wave = threadIdx.x >> 6;
  int wm = wave >> 1, wn = wave & 1, ll = lane & 15, quad = lane >> 4;
#pragma unroll
  for (int mi = 0; mi < 4; ++mi)
#pragma unroll
    for (int ni = 0; ni < 4; ++ni) {
      int kc = kt * 128 + wn * 64 + ni * 16 + ll;
#pragma unroll
      for (int r = 0; r < 4; ++r) {
        int qr = qt * 128 + wm * 64 + mi * 16 + quad * 4 + r;
        float s = acc[mi][ni][r] * 0.03125f;  // 1/sqrt(1024)
        float u = (kc > qr) ? 0.f : __expf(fminf(fmaxf(s, -15.f), 10.f));
        U[((size_t)b * Sv + qr) * Sv + kc] = (_Float16)u;
      }
    }
}

// --- 4. row sums -> 1/l ---
__global__ __launch_bounds__(256) void ca_rowsum(const _Float16* __restrict__ U,
                                                 float* __restrict__ invl) {
  int rg = blockIdx.x;
  int b = rg >> 11, q = rg & (Sv - 1);
  int lim = ((q >> 7) + 1) << 7;
  const _Float16* row = U + ((size_t)b * Sv + q) * Sv;
  float s = 0.f;
  for (int k = threadIdx.x * 8; k < lim; k += 2048) {
    f16x8 v = *(const f16x8*)(row + k);
#pragma unroll
    for (int j = 0; j < 8; ++j) s += (float)v[j];
  }
#pragma unroll
  for (int o = 32; o >= 1; o >>= 1) s += __shfl_down(s, o);
  __shared__ float wsum[4];
  if ((threadIdx.x & 63) == 0) wsum[threadIdx.x >> 6] = s;
  __syncthreads();
  if (threadIdx.x == 0) invl[rg] = 1.f / (wsum[0] + wsum[1] + wsum[2] + wsum[3]);
}

// --- 5. PV GEMM: out = (U @ V) * invl ---
__global__ __launch_bounds__(256) void ca_pv(const _Float16* __restrict__ U,
                                             const _Float16* __restrict__ Vt,
                                             const float* __restrict__ invl,
                                             float* __restrict__ Out) {
  int nt = blockIdx.x, qt = blockIdx.y, b = blockIdx.z;
  __shared__ _Float16 S[4][4096];
  f32x4 acc[4][4];
  ZERO_ACC(acc);
  const _Float16* Ab = U + ((size_t)b * Sv + qt * 128) * Sv;
  const _Float16* Bb = Vt + (size_t)(nt * 128) * (Bv * Sv) + (size_t)b * Sv;
  gemm_dbuf(Ab, Sv, Bb, Bv * Sv, (qt + 1) * 4, S, acc);   // ktiles multiple of 4
  int lane = threadIdx.x & 63, wave = threadIdx.x >> 6;
  int wm = wave >> 1, wn = wave & 1, ll = lane & 15, quad = lane >> 4;
#pragma unroll
  for (int mi = 0; mi < 4; ++mi)
#pragma unroll
    for (int ni = 0; ni < 4; ++ni) {
      int oc = nt * 128 + wn * 64 + ni * 16 + ll;
#pragma unroll
      for (int r = 0; r < 4; ++r) {
        int qr = qt * 128 + wm * 64 + mi * 16 + quad * 4 + r;
        Out[((size_t)b * Sv + qr) * Dv + oc] = acc[mi][ni][r] * invl[b * Sv + qr];
      }
    }
}

extern "C" void kernel_launch(void* const* d_in, const int* in_sizes, int n_in,
                              void* d_out, int out_size, void* d_ws, size_t ws_size,
                              hipStream_t stream) {
  const float* x  = (const float*)d_in[0];
  const float* Wq = (const float*)d_in[1];
  const float* Wk = (const float*)d_in[2];
  const float* Wv = (const float*)d_in[3];
  float* out = (float*)d_out;

  char* ws = (char*)d_ws;
  size_t off = 0;
  const size_t M = (size_t)Bv * Sv;           // 16384
  _Float16* xh  = (_Float16*)(ws + off); off += M * Dv * 2;        // 32 MB
  _Float16* WTq = (_Float16*)(ws + off); off += (size_t)Dv * Dv * 2;
  _Float16* WTk = (_Float16*)(ws + off); off += (size_t)Dv * Dv * 2;
  _Float16* WTv = (_Float16*)(ws + off); off += (size_t)Dv * Dv * 2;
  _Float16* Q   = (_Float16*)(ws + off); off += M * Dv * 2;        // 32 MB
  _Float16* Km  = (_Float16*)(ws + off); off += M * Dv * 2;        // 32 MB
  _Float16* Vt  = (_Float16*)(ws + off); off += M * Dv * 2;        // 32 MB (transposed)
  _Float16* U   = (_Float16*)(ws + off); off += (size_t)Bv * Sv * Sv * 2;  // 64 MB
  float*    invl = (float*)(ws + off);   off += M * 4;

  ca_cast<<<(M * Dv) / (8 * 256), 256, 0, stream>>>(x, xh);
  ca_transpose<<<dim3(32, 32, 3), 256, 0, stream>>>(Wq, Wk, Wv, WTq, WTk, WTv);

  ca_qkv3<<<dim3(768), 512, 0, stream>>>(xh, WTq, WTk, WTv, Q, Km, Vt);

  ca_score<<<dim3(Sv / 128, Sv / 128, Bv), 256, 0, stream>>>(Q, Km, U);
  ca_rowsum<<<M, 256, 0, stream>>>(U, invl);
  ca_pv<<<dim3(Dv / 128, Sv / 128, Bv), 256, 0, stream>>>(U, Vt, invl, out);
}

// Round 4
// 359.636 us; speedup vs baseline: 1.1946x; 1.1266x over previous
//
#include <hip/hip_runtime.h>

// CausalAttention: B=8, S=2048, D_IN=D_OUT=1024, single head, causal, fp32 I/O.
// Pipeline (all fp16 MFMA 16x16x32, fp32 accum):
//   1. cast x -> xh (fp16); transpose+cast Wq,Wk,Wv -> WT (d_out-major, fp16)
//   2. ca_qkv3: fused QKV GEMM (R7 fine-phase engine, unchanged).
//   3. ca_score2: U = exp(QK^T/32), 256^2 tiles, fine-phase engine (R8)
//   4. ca_rowsum: invl[b,q] = 1/sum_k U
//   5. ca_pv2: out = (U @ V) * invl, 256^2 tiles, fine-phase engine (R8)
//
// R8: port score+pv onto the R7-verified 256^2 fine-phase engine (gemm_fine):
//  - engine kept byte-identical to R7's TILEG (slots, stage order, vmcnt
//    gates, PH_OPEN fences); parametrized by per-matrix strides and a
//    runtime-even NT (pv: NT=(qt+1)*4 in {4..32}; tail pair = same G=0/G=2).
//  - score2: grid 8x8x8 causal (288 active blocks, NT=16); writes zeros
//    above the diagonal across the full 256^2 tile (U semantics unchanged).
//  - pv2: grid 4x8x8 = 256 blocks; B=Vt staging is now 128B-contiguous per
//    row (fixes the old 64B-granule coalescing).
// Engine recap (verified R7): 256x256 tile, 512 thr / 8 waves (2Mx4N), BK=64
// K-tiles, 4 phases/tile, 16 MFMA/phase, 2 barriers/phase; LDS = 8 half-slot
// ring (128 KiB, 2-tile dbuf); stages A0(t+1)@p0, A1(t+1)@p1, B1(t+1)@p2,
// B0(t+2)@p3; gate s_waitcnt vmcnt(2) once per tile (vmcnt(0) only at the
// second-to-last tile); T2 16B-chunk XOR swizzle pc = c ^ (row&7) on both
// sides; setprio around MFMA clusters.

#define Bv 8
#define Sv 2048
#define Dv 1024
#define NTQ 16  // K64 tiles in the QKV/score GEMMs (1024/64)

typedef _Float16 f16x8 __attribute__((ext_vector_type(8)));
typedef _Float16 f16x4 __attribute__((ext_vector_type(4)));
typedef float    f32x4 __attribute__((ext_vector_type(4)));

#define GLL(gp, lp)                                            \
  __builtin_amdgcn_global_load_lds(                            \
      (const __attribute__((address_space(1))) void*)(gp),     \
      (__attribute__((address_space(3))) void*)(lp), 16, 0, 0)

// --- 1a. cast x (fp32) -> fp16, 8 elems/thread ---
__global__ __launch_bounds__(256) void ca_cast(const float* __restrict__ x,
                                               _Float16* __restrict__ y) {
  int i = (blockIdx.x * 256 + threadIdx.x) * 8;
  f32x4 a = *(const f32x4*)(x + i);
  f32x4 b = *(const f32x4*)(x + i + 4);
  f16x8 h;
#pragma unroll
  for (int j = 0; j < 4; ++j) { h[j] = (_Float16)a[j]; h[4 + j] = (_Float16)b[j]; }
  *(f16x8*)(y + i) = h;
}

// --- 1b. transpose+cast W (K x N fp32) -> WT (N x K fp16) ---
__global__ __launch_bounds__(256) void ca_transpose(const float* __restrict__ W0,
                                                    const float* __restrict__ W1,
                                                    const float* __restrict__ W2,
                                                    _Float16* __restrict__ T0,
                                                    _Float16* __restrict__ T1,
                                                    _Float16* __restrict__ T2) {
  const float* W = blockIdx.z == 0 ? W0 : blockIdx.z == 1 ? W1 : W2;
  _Float16* WT   = blockIdx.z == 0 ? T0 : blockIdx.z == 1 ? T1 : T2;
  __shared__ _Float16 t[32][33];
  int k0 = blockIdx.x * 32, n0 = blockIdx.y * 32;
  int r = threadIdx.x >> 5, c = threadIdx.x & 31;
#pragma unroll
  for (int i = 0; i < 4; ++i)
    t[r + i * 8][c] = (_Float16)W[(size_t)(k0 + r + i * 8) * Dv + n0 + c];
  __syncthreads();
#pragma unroll
  for (int i = 0; i < 4; ++i)
    WT[(size_t)(n0 + r + i * 8) * Dv + k0 + c] = t[c][r + i * 8];
}

// ---------------------------------------------------------------------------
// R7/R8 fine-phase 256x256 GEMM engine.  A: [256 x K] row-major (ldA),
// B: [256 x K] row-major (ldB), C += A @ B^T over K = NTt*64 (NTt even >= 4).
// Caller provides L (8 x 8192 f16 = 128 KiB) and acc[8][4] (zeroed).
// ---------------------------------------------------------------------------
__device__ __forceinline__ void gemm_fine(const _Float16* __restrict__ gA, int ldA,
                                          const _Float16* __restrict__ gB, long ldB,
                                          int NTt, _Float16 (*L)[8192],
                                          f32x4 acc[8][4]) {
  const int tid  = threadIdx.x;
  const int lane = tid & 63, wave = tid >> 6;
  const int wm = wave >> 2, wn = wave & 3;          // 2M x 4N waves, tile 128x64
  const int ll = lane & 15, quad = lane >> 4;

  // staging geometry (pre-swizzled global source; linear GLL dest)
  const int laneRow = wave * 8 + (lane >> 3);
  const int laneCol = (((lane & 7) ^ ((lane >> 3) & 7)) << 3);  // elems
  const long aOff0 = (long)laneRow * ldA + laneCol;
  const long aOff1 = (long)(64 + laneRow) * ldA + laneCol;
  const long bOff0 = (long)laneRow * ldB + laneCol;
  const long bOff1 = (long)(64 + laneRow) * ldB + laneCol;
  _Float16* Ldst = &L[0][0] + wave * 512;           // wave-uniform

  // read geometry: frag (row, ks): phys chunk = (ks*4+quad)^(ll&7)
  const int sw0 = ((quad ^ (ll & 7)) << 3);         // ks=0, elems
  _Float16* Lb = &L[0][0];
  const _Float16* pA0 = Lb + wm * 8192 + ll * 64 + sw0;
  const _Float16* pA1 = Lb + wm * 8192 + ll * 64 + (sw0 ^ 32);
  const _Float16* pB0 = Lb + 16384 + (wn >> 1) * 8192 + (wn & 1) * 4096 + ll * 64 + sw0;
  const _Float16* pB1 = Lb + 16384 + (wn >> 1) * 8192 + (wn & 1) * 4096 + ll * 64 + (sw0 ^ 32);

#define STGA(slot, ht, kpf)                                       \
  do {                                                            \
    const _Float16* g_ = gA + (long)(ht) * 128 * ldA + (long)(kpf) * 64; \
    GLL(g_ + aOff0, Ldst + (slot) * 8192);                        \
    GLL(g_ + aOff1, Ldst + (slot) * 8192 + 4096);                 \
  } while (0)
#define STGB(slot, ht, kpf)                                       \
  do {                                                            \
    const _Float16* g_ = gB + (long)(ht) * 128 * ldB + (long)(kpf) * 64; \
    GLL(g_ + bOff0, Ldst + (slot) * 8192);                        \
    GLL(g_ + bOff1, Ldst + (slot) * 8192 + 4096);                 \
  } while (0)
#define RD_A(P, d, mh)                                            \
  _Pragma("unroll") for (int i_ = 0; i_ < 4; ++i_)                \
      a[i_] = *(const f16x8*)((P) + (d) * 32768 + ((mh) * 4 + i_) * 1024);
#define RD_B(P, d)                                                \
  _Pragma("unroll") for (int i_ = 0; i_ < 4; ++i_)                \
      b[i_] = *(const f16x8*)((P) + (d) * 32768 + i_ * 1024);
#define MMA(mh)                                                   \
  __builtin_amdgcn_s_setprio(1);                                  \
  _Pragma("unroll") for (int i_ = 0; i_ < 4; ++i_)                \
  _Pragma("unroll") for (int j_ = 0; j_ < 4; ++j_)                \
      acc[(mh) * 4 + i_][j_] = __builtin_amdgcn_mfma_f32_16x16x32_f16( \
          a[i_], b[j_], acc[(mh) * 4 + i_][j_], 0, 0, 0);         \
  __builtin_amdgcn_s_setprio(0);
#define BAR() __builtin_amdgcn_s_barrier()
#define WAITV_(n) asm volatile("s_waitcnt vmcnt(" #n ")" ::: "memory")
#define WAITV(n) WAITV_(n)
#define PH_OPEN()                                                 \
  BAR();                                                          \
  asm volatile("s_waitcnt lgkmcnt(0)" ::: "memory");              \
  __builtin_amdgcn_sched_barrier(0)

  // Per tile (kk, parity d): 4 phases {ds_read; stage 1 half; PH_OPEN; MFMA;
  // bar}. p0: A[mh0,ks0]+B[ks0], stage A0(kk+1); p1: A[mh1,ks0], stage
  // A1(kk+1); p2: A[mh0,ks1]+B[ks1], stage B1(kk+1); p3: A[mh1,ks1], stage
  // B0(kk+2). sched_barrier(0) before p3 pins its DMA below slot-4d+2 reads.
#define TILEG(kk, d, G)                                           \
  do {                                                            \
    f16x8 a[4], b[4];                                             \
    RD_A(pA0, d, 0); RD_B(pB0, d);                                \
    if ((kk) + 1 < NTt) STGA(4 * (1 - (d)) + 0, 0, (kk) + 1);     \
    PH_OPEN(); MMA(0); BAR();                                     \
    RD_A(pA0, d, 1);                                              \
    if ((kk) + 1 < NTt) STGA(4 * (1 - (d)) + 1, 1, (kk) + 1);     \
    PH_OPEN(); MMA(1); BAR();                                     \
    RD_A(pA1, d, 0); RD_B(pB1, d);                                \
    if ((kk) + 1 < NTt) STGB(4 * (1 - (d)) + 3, 1, (kk) + 1);     \
    PH_OPEN(); MMA(0); BAR();                                     \
    __builtin_amdgcn_sched_barrier(0);                            \
    RD_A(pA1, d, 1);                                              \
    if ((kk) + 2 < NTt) STGB(4 * (d) + 2, 0, (kk) + 2);           \
    PH_OPEN(); MMA(1);                                            \
    WAITV(G); BAR();                                              \
    __builtin_amdgcn_sched_barrier(0);                            \
  } while (0)

  // Prologue: stage B0(0),A0(0),A1(0),B1(0),B0(1) (oldest-first), gate.
  STGB(2, 0, 0);
  STGA(0, 0, 0);
  STGA(1, 1, 0);
  STGB(3, 1, 0);
  STGB(6, 0, 1);
  WAITV(2); BAR();
  __builtin_amdgcn_sched_barrier(0);

#pragma unroll 1
  for (int kk = 0; kk < NTt - 2; kk += 2) {   // tiles 0..NTt-3
    TILEG(kk, 0, 2);
    TILEG(kk + 1, 1, 2);
  }
  TILEG(NTt - 2, 0, 0);   // tail: drain fully once
  TILEG(NTt - 1, 1, 2);

#undef TILEG
#undef PH_OPEN
#undef MMA
#undef RD_A
#undef RD_B
#undef STGB
#undef STGA
}

#define ZERO8x4(acc)                               \
  _Pragma("unroll") for (int i_ = 0; i_ < 8; ++i_) \
  _Pragma("unroll") for (int j_ = 0; j_ < 4; ++j_) \
      acc[i_][j_] = (f32x4){0.f, 0.f, 0.f, 0.f};

// ---------------------------------------------------------------------------
// --- 2. R7 fused QKV projection (unchanged): 768 blocks x 512 thr.
// nt = 0..11 of 256 cols: 0-3 Q, 4-7 K, 8-11 V.
// ---------------------------------------------------------------------------
__global__ __launch_bounds__(512, 2) void ca_qkv3(const _Float16* __restrict__ X,
                                                  const _Float16* __restrict__ WTq,
                                                  const _Float16* __restrict__ WTk,
                                                  const _Float16* __restrict__ WTv,
                                                  _Float16* __restrict__ Q,
                                                  _Float16* __restrict__ K,
                                                  _Float16* __restrict__ Vt) {
  __shared__ _Float16 L[8][8192];

  // XCD-chunked bijective swizzle: 768 % 8 == 0.
  int id  = blockIdx.x;
  int swz = (id & 7) * 96 + (id >> 3);
  int my  = swz / 12, nt = swz - my * 12;
  int m0  = my * 256;
  int which = nt >> 2;
  int n0  = (nt & 3) * 256;
  const _Float16* WT = which == 0 ? WTq : which == 1 ? WTk : WTv;

  f32x4 acc[8][4];
  ZERO8x4(acc);
  gemm_fine(X + (size_t)m0 * Dv, Dv, WT + (size_t)n0 * Dv, Dv, NTQ, L, acc);

  const int lane = threadIdx.x & 63, wave = threadIdx.x >> 6;
  const int wm = wave >> 2, wn = wave & 3;
  const int ll = lane & 15, quad = lane >> 4;
  if (which < 2) {
    _Float16* Out = which == 0 ? Q : K;
#pragma unroll
    for (int mi = 0; mi < 8; ++mi)
#pragma unroll
      for (int ni = 0; ni < 4; ++ni) {
        int gc = n0 + wn * 64 + ni * 16 + ll;
#pragma unroll
        for (int r = 0; r < 4; ++r) {
          int gr = m0 + wm * 128 + mi * 16 + quad * 4 + r;
          Out[(size_t)gr * Dv + gc] = (_Float16)acc[mi][ni][r];
        }
      }
  } else {
    // Vt: [d_out][B*S]; 4 regs = 4 consecutive rows -> contiguous 8B store
#pragma unroll
    for (int mi = 0; mi < 8; ++mi)
#pragma unroll
      for (int ni = 0; ni < 4; ++ni) {
        int gc = n0 + wn * 64 + ni * 16 + ll;
        int gr = m0 + wm * 128 + mi * 16 + quad * 4;
        f16x4 v;
#pragma unroll
        for (int r = 0; r < 4; ++r) v[r] = (_Float16)acc[mi][ni][r];
        *(f16x4*)(Vt + (size_t)gc * (Bv * Sv) + gr) = v;
      }
  }
}

// ---------------------------------------------------------------------------
// --- 3. R8 scores: U = exp(QK^T / 32), 256^2 tiles, causal blocks only ---
// grid (8,8,8): kt, qt, b.  288 active blocks (kt <= qt), NT=16.
// ---------------------------------------------------------------------------
__global__ __launch_bounds__(512, 2) void ca_score2(const _Float16* __restrict__ Q,
                                                    const _Float16* __restrict__ Km,
                                                    _Float16* __restrict__ U) {
  int kt = blockIdx.x, qt = blockIdx.y, b = blockIdx.z;
  if (kt > qt) return;
  __shared__ _Float16 L[8][8192];
  f32x4 acc[8][4];
  ZERO8x4(acc);
  const _Float16* Qb = Q + ((size_t)b * Sv + qt * 256) * Dv;
  const _Float16* Kb = Km + ((size_t)b * Sv + kt * 256) * Dv;
  gemm_fine(Qb, Dv, Kb, Dv, NTQ, L, acc);

  const int lane = threadIdx.x & 63, wave = threadIdx.x >> 6;
  const int wm = wave >> 2, wn = wave & 3;
  const int ll = lane & 15, quad = lane >> 4;
#pragma unroll
  for (int mi = 0; mi < 8; ++mi)
#pragma unroll
    for (int ni = 0; ni < 4; ++ni) {
      int kc = kt * 256 + wn * 64 + ni * 16 + ll;
#pragma unroll
      for (int r = 0; r < 4; ++r) {
        int qr = qt * 256 + wm * 128 + mi * 16 + quad * 4 + r;
        float s = acc[mi][ni][r] * 0.03125f;  // 1/sqrt(1024)
        float u = (kc > qr) ? 0.f : __expf(fminf(fmaxf(s, -15.f), 10.f));
        U[((size_t)b * Sv + qr) * Sv + kc] = (_Float16)u;
      }
    }
}

// --- 4. row sums -> 1/l (unchanged) ---
__global__ __launch_bounds__(256) void ca_rowsum(const _Float16* __restrict__ U,
                                                 float* __restrict__ invl) {
  int rg = blockIdx.x;
  int b = rg >> 11, q = rg & (Sv - 1);
  int lim = ((q >> 7) + 1) << 7;
  const _Float16* row = U + ((size_t)b * Sv + q) * Sv;
  float s = 0.f;
  for (int k = threadIdx.x * 8; k < lim; k += 2048) {
    f16x8 v = *(const f16x8*)(row + k);
#pragma unroll
    for (int j = 0; j < 8; ++j) s += (float)v[j];
  }
#pragma unroll
  for (int o = 32; o >= 1; o >>= 1) s += __shfl_down(s, o);
  __shared__ float wsum[4];
  if ((threadIdx.x & 63) == 0) wsum[threadIdx.x >> 6] = s;
  __syncthreads();
  if (threadIdx.x == 0) invl[rg] = 1.f / (wsum[0] + wsum[1] + wsum[2] + wsum[3]);
}

// ---------------------------------------------------------------------------
// --- 5. R8 PV GEMM: out = (U @ V) * invl, 256^2 tiles ---
// grid (4,8,8): nt, qt, b.  NT = (qt+1)*4 K64-tiles (even, 4..32).
// ---------------------------------------------------------------------------
__global__ __launch_bounds__(512, 2) void ca_pv2(const _Float16* __restrict__ U,
                                                 const _Float16* __restrict__ Vt,
                                                 const float* __restrict__ invl,
                                                 float* __restrict__ Out) {
  int nt = blockIdx.x, qt = blockIdx.y, b = blockIdx.z;
  __shared__ _Float16 L[8][8192];
  f32x4 acc[8][4];
  ZERO8x4(acc);
  const _Float16* Ab = U + ((size_t)b * Sv + qt * 256) * Sv;
  const _Float16* Bb = Vt + (size_t)(nt * 256) * (Bv * Sv) + (size_t)b * Sv;
  gemm_fine(Ab, Sv, Bb, (long)Bv * Sv, (qt + 1) * 4, L, acc);

  const int lane = threadIdx.x & 63, wave = threadIdx.x >> 6;
  const int wm = wave >> 2, wn = wave & 3;
  const int ll = lane & 15, quad = lane >> 4;
#pragma unroll
  for (int mi = 0; mi < 8; ++mi)
#pragma unroll
    for (int ni = 0; ni < 4; ++ni) {
      int oc = nt * 256 + wn * 64 + ni * 16 + ll;
#pragma unroll
      for (int r = 0; r < 4; ++r) {
        int qr = qt * 256 + wm * 128 + mi * 16 + quad * 4 + r;
        Out[((size_t)b * Sv + qr) * Dv + oc] = acc[mi][ni][r] * invl[b * Sv + qr];
      }
    }
}

extern "C" void kernel_launch(void* const* d_in, const int* in_sizes, int n_in,
                              void* d_out, int out_size, void* d_ws, size_t ws_size,
                              hipStream_t stream) {
  const float* x  = (const float*)d_in[0];
  const float* Wq = (const float*)d_in[1];
  const float* Wk = (const float*)d_in[2];
  const float* Wv = (const float*)d_in[3];
  float* out = (float*)d_out;

  char* ws = (char*)d_ws;
  size_t off = 0;
  const size_t M = (size_t)Bv * Sv;           // 16384
  _Float16* xh  = (_Float16*)(ws + off); off += M * Dv * 2;        // 32 MB
  _Float16* WTq = (_Float16*)(ws + off); off += (size_t)Dv * Dv * 2;
  _Float16* WTk = (_Float16*)(ws + off); off += (size_t)Dv * Dv * 2;
  _Float16* WTv = (_Float16*)(ws + off); off += (size_t)Dv * Dv * 2;
  _Float16* Q   = (_Float16*)(ws + off); off += M * Dv * 2;        // 32 MB
  _Float16* Km  = (_Float16*)(ws + off); off += M * Dv * 2;        // 32 MB
  _Float16* Vt  = (_Float16*)(ws + off); off += M * Dv * 2;        // 32 MB (transposed)
  _Float16* U   = (_Float16*)(ws + off); off += (size_t)Bv * Sv * Sv * 2;  // 64 MB
  float*    invl = (float*)(ws + off);   off += M * 4;

  ca_cast<<<(M * Dv) / (8 * 256), 256, 0, stream>>>(x, xh);
  ca_transpose<<<dim3(32, 32, 3), 256, 0, stream>>>(Wq, Wk, Wv, WTq, WTk, WTv);

  ca_qkv3<<<dim3(768), 512, 0, stream>>>(xh, WTq, WTk, WTv, Q, Km, Vt);

  ca_score2<<<dim3(8, 8, Bv), 512, 0, stream>>>(Q, Km, U);
  ca_rowsum<<<M, 256, 0, stream>>>(U, invl);
  ca_pv2<<<dim3(4, 8, Bv), 512, 0, stream>>>(U, Vt, invl, out);
}